// Round 18
// baseline (1272.838 us; speedup 1.0000x reference)
//
#include <hip/hip_runtime.h>
#include <math.h>

typedef short bfrag __attribute__((ext_vector_type(8)));   // 8 bf16 (4 VGPR)
typedef float ffrag __attribute__((ext_vector_type(4)));   // 4 f32 accum

#define MFMA16(a, b, c) __builtin_amdgcn_mfma_f32_16x16x32_bf16((a), (b), (c), 0, 0, 0)

// Pre-transposed bf16 weights ([outcol][k] row-major), built once by conv_w.
// qkv @0 (768x256), proj @196608 (256x256), w1 @262144 (1024x256), w2 @524288 (256x1024)
__device__ __align__(16) unsigned short g_wt[786432];

__device__ __forceinline__ unsigned bf16b(float f) {   // fp32 -> bf16 bits, RNE
  unsigned u = __float_as_uint(f);
  return (u + 0x7FFFu + ((u >> 16) & 1u)) >> 16;
}
__device__ __forceinline__ unsigned pk2(float lo, float hi) {
  return bf16b(lo) | (bf16b(hi) << 16);
}
__device__ __forceinline__ float bf2f(unsigned u) {
  return __uint_as_float(u << 16);
}
// tanh-form GELU with HW reciprocal (numerics proven: absmax 0.03125 in R8/R17).
__device__ __forceinline__ float gelu_f(float u) {
  const float z = 1.5957691216057308f * (u + 0.044715f * u * u * u);
  return u * __builtin_amdgcn_rcpf(1.f + __expf(-z));
}

__global__ void conv_w(const float* __restrict__ qkv_w, const float* __restrict__ proj_w,
                       const float* __restrict__ w1, const float* __restrict__ w2) {
  const int idx = blockIdx.x * 256 + threadIdx.x;   // 393216 (c,k2) pairs
  const float* src; int c, k2, C, K, ofs;
  if (idx < 98304)       { src = qkv_w;  C = 768;  K = 256;  c = idx % 768;  k2 = idx / 768;  ofs = 0; }
  else if (idx < 131072) { int i = idx - 98304;  src = proj_w; C = 256;  K = 256;  c = i % 256;  k2 = i / 256;  ofs = 196608; }
  else if (idx < 262144) { int i = idx - 131072; src = w1;     C = 1024; K = 256;  c = i % 1024; k2 = i / 1024; ofs = 262144; }
  else                   { int i = idx - 262144; src = w2;     C = 256;  K = 1024; c = i % 256;  k2 = i / 256;  ofs = 524288; }
  const float lo = src[(2 * k2) * C + c];
  const float hi = src[(2 * k2 + 1) * C + c];
  *(unsigned*)&g_wt[ofs + c * K + 2 * k2] = pk2(lo, hi);
}

// Byte offset into [*][C] bf16 LDS tile, XOR-swizzled per 16B slot (C>=64: 8 slots).
__device__ __forceinline__ int swz(int row, int col, int C) {
  return row * (C * 2) + ((((col >> 3) ^ (row & 7)) << 4) + ((col & 7) << 1));
}
__device__ __forceinline__ bfrag ldfrag(const char* lds, int outer, int k0, int C) {
  const int l = threadIdx.x & 63;
  return *(const bfrag*)(lds + swz(outer + (l & 15), k0 + ((l >> 4) << 3), C));
}

// Stage a [128][128] bf16 tile (32KB): linear LDS dest + inverse-swizzled source.
__device__ __forceinline__ void stage128(char* lds, const unsigned short* __restrict__ src,
                                         long rowBase, int strideShorts, int kOfs) {
  const int wv = threadIdx.x >> 6, l = threadIdx.x & 63;
  #pragma unroll
  for (int p = 0; p < 4; ++p) {
    const int base = wv * 1024 + p * 8192;
    const int off = base + l * 16;
    const int row = off >> 8;
    const int ss = ((off & 255) >> 4) ^ (row & 7);
    const unsigned short* g = src + (rowBase + row) * (long)strideShorts + kOfs + ss * 8;
    __builtin_amdgcn_global_load_lds((const __attribute__((address_space(1))) void*)g,
                                     (__attribute__((address_space(3))) void*)(lds + base),
                                     16, 0, 0);
  }
}

// Generic weight-tile stage. DSTROWB = LDS row bytes; slot-XOR mask 7 (matches swz).
template <int DSTROWB>
__device__ __forceinline__ void glds_stage(char* lds, const unsigned short* src,
                                           int srcRowShorts, int bytes) {
  const int wv = threadIdx.x >> 6, l = threadIdx.x & 63;
  for (int base = wv * 1024; base < bytes; base += 8192) {
    const int off = base + l * 16;
    const int row = off / DSTROWB;
    const int slot = (off % DSTROWB) >> 4;
    const int ss = slot ^ (row & 7);
    const unsigned short* g = src + row * srcRowShorts + ss * 8;
    __builtin_amdgcn_global_load_lds((const __attribute__((address_space(1))) void*)g,
                                     (__attribute__((address_space(3))) void*)(lds + base),
                                     16, 0, 0);
  }
}

// 128x128 tile core over one BK=128 chunk (C=128 LDS tiles), 4 k-steps.
__device__ __forceinline__ void mm_core128(const char* AX, const char* BW, ffrag acc[2][4]) {
  const int wv = threadIdx.x >> 6;
  const int rh = wv >> 2, cq = wv & 3;
  #pragma unroll
  for (int ks = 0; ks < 4; ++ks) {
    const bfrag aw0 = ldfrag(BW, cq * 32, ks * 32, 128);
    const bfrag aw1 = ldfrag(BW, cq * 32 + 16, ks * 32, 128);
    #pragma unroll
    for (int nt = 0; nt < 4; ++nt) {
      const bfrag xb = ldfrag(AX, rh * 64 + nt * 16, ks * 32, 128);
      acc[0][nt] = MFMA16(aw0, xb, acc[0][nt]);
      acc[1][nt] = MFMA16(aw1, xb, acc[1][nt]);
    }
  }
}

// Wave-per-row LayerNorm: 4 elems/lane in, two packed bf16 words out.
__device__ __forceinline__ void ln_pack(float d0, float d1, float d2, float d3,
                                        const float* g, const float* bb, int lane,
                                        unsigned& o0, unsigned& o1) {
  float s = d0 + d1 + d2 + d3;
  #pragma unroll
  for (int o = 32; o; o >>= 1) s += __shfl_xor(s, o);
  const float mu = s * (1.f / 256.f);
  d0 -= mu; d1 -= mu; d2 -= mu; d3 -= mu;
  float q = d0 * d0 + d1 * d1 + d2 * d2 + d3 * d3;
  #pragma unroll
  for (int o = 32; o; o >>= 1) q += __shfl_xor(q, o);
  const float vv = q * (1.f / 256.f) + 1e-5f;
  float rs = rsqrtf(vv);
  rs = rs * (1.5f - 0.5f * vv * rs * rs);
  const float4 g4 = *(const float4*)(g + lane * 4);
  const float4 b4 = *(const float4*)(bb + lane * 4);
  o0 = pk2(d0 * rs * g4.x + b4.x, d1 * rs * g4.y + b4.y);
  o1 = pk2(d2 * rs * g4.z + b4.z, d3 * rs * g4.w + b4.w);
}

// LN1 for one batch-group: 8192 blocks x 8 rows.
__global__ __launch_bounds__(512) void ln1_k(const float* __restrict__ x,
    const float* __restrict__ g, const float* __restrict__ bb,
    unsigned short* __restrict__ XB, long rowOfs) {
  const int wv = threadIdx.x >> 6, l = threadIdx.x & 63;
  const long lrow = (long)blockIdx.x * 8 + wv;
  const float4 v = *(const float4*)(x + (rowOfs + lrow) * 256 + l * 4);
  unsigned o0, o1;
  ln_pack(v.x, v.y, v.z, v.w, g, bb, l, o0, o1);
  unsigned short* dp = XB + lrow * 256 + l * 4;
  *(unsigned*)dp = o0; *(unsigned*)(dp + 2) = o1;
}

// qkv GEMM for one group: grid (512, 6). BK=128 x2, 64KB LDS, 2 blocks/CU.
__global__ __launch_bounds__(512, 4) void gemm_qkv(const unsigned short* __restrict__ XB,
    const float* __restrict__ qkv_b, unsigned short* __restrict__ QKV) {
  __shared__ __align__(16) char smem[65536];
  char* AX = smem; char* BW = smem + 32768;
  const int mb = blockIdx.x, nb = blockIdx.y;
  ffrag acc[2][4];
  #pragma unroll
  for (int a = 0; a < 2; ++a)
    #pragma unroll
    for (int n = 0; n < 4; ++n) { ffrag z = {0.f, 0.f, 0.f, 0.f}; acc[a][n] = z; }
  #pragma unroll
  for (int kc = 0; kc < 2; ++kc) {
    stage128(AX, XB, (long)mb * 128, 256, kc * 128);
    stage128(BW, g_wt, (long)nb * 128, 256, kc * 128);
    __syncthreads();
    mm_core128(AX, BW, acc);
    __syncthreads();
  }
  const int l = threadIdx.x & 63, wv = threadIdx.x >> 6;
  const int rh = wv >> 2, cq = wv & 3;
  const float sc = (nb < 2) ? 0.17677669529663687f : 1.f;   // Q pre-scale
  #pragma unroll
  for (int mt = 0; mt < 2; ++mt) {
    const int cg = nb * 128 + cq * 32 + mt * 16 + ((l >> 4) << 2);
    const float4 bq = *(const float4*)(qkv_b + cg);
    #pragma unroll
    for (int nt = 0; nt < 4; ++nt) {
      const long row = (long)mb * 128 + rh * 64 + nt * 16 + (l & 15);
      unsigned short* dp = QKV + row * 768 + cg;
      *(unsigned*)dp       = pk2((acc[mt][nt][0] + bq.x) * sc, (acc[mt][nt][1] + bq.y) * sc);
      *(unsigned*)(dp + 2) = pk2((acc[mt][nt][2] + bq.z) * sc, (acc[mt][nt][3] + bq.w) * sc);
    }
  }
}

// proj GEMM: full M=262144, grid (2048, 2). BK=128 x2, 2 blocks/CU.
__global__ __launch_bounds__(512, 4) void gemm_proj(const unsigned short* __restrict__ O,
    const float* __restrict__ proj_b, unsigned short* __restrict__ outw) {
  __shared__ __align__(16) char smem[65536];
  char* AX = smem; char* BW = smem + 32768;
  const int mb = blockIdx.x, nb = blockIdx.y;
  ffrag acc[2][4];
  #pragma unroll
  for (int a = 0; a < 2; ++a)
    #pragma unroll
    for (int n = 0; n < 4; ++n) { ffrag z = {0.f, 0.f, 0.f, 0.f}; acc[a][n] = z; }
  #pragma unroll
  for (int kc = 0; kc < 2; ++kc) {
    stage128(AX, O, (long)mb * 128, 256, kc * 128);
    stage128(BW, g_wt + 196608, (long)nb * 128, 256, kc * 128);
    __syncthreads();
    mm_core128(AX, BW, acc);
    __syncthreads();
  }
  const int l = threadIdx.x & 63, wv = threadIdx.x >> 6;
  const int rh = wv >> 2, cq = wv & 3;
  #pragma unroll
  for (int mt = 0; mt < 2; ++mt) {
    const int cg = nb * 128 + cq * 32 + mt * 16 + ((l >> 4) << 2);
    const float4 pb = *(const float4*)(proj_b + cg);
    #pragma unroll
    for (int nt = 0; nt < 4; ++nt) {
      const long row = (long)mb * 128 + rh * 64 + nt * 16 + (l & 15);
      unsigned short* dp = outw + row * 256 + cg;
      *(unsigned*)dp       = pk2(acc[mt][nt][0] + pb.x, acc[mt][nt][1] + pb.y);
      *(unsigned*)(dp + 2) = pk2(acc[mt][nt][2] + pb.z, acc[mt][nt][3] + pb.w);
    }
  }
}

// ---- attention core: one block per 8x8 window (1024 blocks/group) ----
// LDS 80KB: KL[64][256] 32K | VT[256][64] 32K | PB 8 x [16][64] 16K  -> 2 blocks/CU
__global__ __launch_bounds__(512, 4) void attn_core(const unsigned short* __restrict__ QKV,
    const float* __restrict__ rpb, unsigned short* __restrict__ O, int bofs) {
  __shared__ __align__(16) char smem[81920];
  char* KL = smem;
  char* VT = smem + 32768;
  char* PB = smem + 65536;
  const int t = threadIdx.x, wv = t >> 6, l = t & 63;
  const int blk = blockIdx.x;
  const int b = blk >> 8, w = blk & 255;   // b = local batch 0..3
  const int wi = w >> 4, wj = w & 15;
  const int bi0 = wi * 8 + 4, bj0 = wj * 8 + 4;
  const ffrag ZERO4 = {0.f, 0.f, 0.f, 0.f};

  #define SROW(r) (((long)b << 14) + (((bi0 + ((r) >> 3)) & 127) << 7) + ((bj0 + ((r) & 7)) & 127))
  #define GROW(r) (((long)(bofs + b) << 14) + (((bi0 + ((r) >> 3)) & 127) << 7) + ((bj0 + ((r) & 7)) & 127))

  // stage K rows -> KL (swizzled via pre-swizzled source)
  #pragma unroll
  for (int p = 0; p < 4; ++p) {
    const int base = wv * 1024 + p * 8192;
    const int off = base + l * 16;
    const int kv = off >> 9;
    const int ss = ((off & 511) >> 4) ^ (kv & 7);
    const unsigned short* g = QKV + SROW(kv) * 768 + 256 + ss * 8;
    __builtin_amdgcn_global_load_lds((const __attribute__((address_space(1))) void*)g,
                                     (__attribute__((address_space(3))) void*)(KL + base),
                                     16, 0, 0);
  }

  // stage V -> VT transposed (packed b32 writes)
  {
    const int rp = t & 31, dh = t >> 5;              // row-pair, d-hextet
    const unsigned short* v0p = QKV + SROW(2 * rp) * 768 + 512 + dh * 16;
    const unsigned short* v1p = QKV + SROW(2 * rp + 1) * 768 + 512 + dh * 16;
    const bfrag a0 = *(const bfrag*)v0p, a1 = *(const bfrag*)(v0p + 8);
    const bfrag c0 = *(const bfrag*)v1p, c1 = *(const bfrag*)(v1p + 8);
    #pragma unroll
    for (int j = 0; j < 8; ++j) {
      const unsigned w0 = ((unsigned)(unsigned short)a0[j]) | (((unsigned)(unsigned short)c0[j]) << 16);
      const unsigned w1 = ((unsigned)(unsigned short)a1[j]) | (((unsigned)(unsigned short)c1[j]) << 16);
      *(unsigned*)(VT + swz(dh * 16 + j, 2 * rp, 64)) = w0;
      *(unsigned*)(VT + swz(dh * 16 + 8 + j, 2 * rp, 64)) = w1;
    }
  }
  __syncthreads();

  const int qt = wv & 3, hh = wv >> 2;
  char* myPB = PB + wv * 2048;
  const int colb = l & 15;
  const int rbase = qt * 16 + ((l >> 4) << 2);

  for (int i = 0; i < 4; ++i) {
    const int h = 2 * i + hh;
    const int hk = h * 32;
    const int qr = qt * 16 + (l & 15);
    const bfrag aq = *(const bfrag*)(QKV + SROW(qr) * 768 + hk + ((l >> 4) << 3));
    ffrag s[4];
    #pragma unroll
    for (int nt = 0; nt < 4; ++nt) {
      const bfrag bk = ldfrag(KL, nt * 16, hk, 256);
      s[nt] = MFMA16(aq, bk, ZERO4);
    }
    float pr[4][4], mx[4], sm[4];
    #pragma unroll
    for (int reg = 0; reg < 4; ++reg) mx[reg] = -3e38f;
    #pragma unroll
    for (int nt = 0; nt < 4; ++nt)
      #pragma unroll
      for (int reg = 0; reg < 4; ++reg) {
        const int rr = rbase + reg, cc = nt * 16 + colb;
        const int idx = ((rr >> 3) - (cc >> 3) + 7) * 15 + ((rr & 7) - (cc & 7) + 7);
        pr[nt][reg] = s[nt][reg] + rpb[idx * 8 + h];
        mx[reg] = fmaxf(mx[reg], pr[nt][reg]);
      }
    #pragma unroll
    for (int reg = 0; reg < 4; ++reg) {
      #pragma unroll
      for (int o = 1; o < 16; o <<= 1) mx[reg] = fmaxf(mx[reg], __shfl_xor(mx[reg], o));
      sm[reg] = 0.f;
    }
    #pragma unroll
    for (int nt = 0; nt < 4; ++nt)
      #pragma unroll
      for (int reg = 0; reg < 4; ++reg) {
        pr[nt][reg] = __expf(pr[nt][reg] - mx[reg]);
        sm[reg] += pr[nt][reg];
      }
    #pragma unroll
    for (int reg = 0; reg < 4; ++reg) {
      #pragma unroll
      for (int o = 1; o < 16; o <<= 1) sm[reg] += __shfl_xor(sm[reg], o);
      sm[reg] = 1.f / sm[reg];
    }
    #pragma unroll
    for (int nt = 0; nt < 4; ++nt)
      #pragma unroll
      for (int reg = 0; reg < 4; ++reg)
        *(unsigned short*)(myPB + swz(((l >> 4) << 2) + reg, nt * 16 + colb, 64)) =
            (unsigned short)bf16b(pr[nt][reg] * sm[reg]);

    ffrag o0 = ZERO4, o1 = ZERO4;
    #pragma unroll
    for (int ks = 0; ks < 2; ++ks) {
      const bfrag ap = ldfrag(myPB, 0, ks * 32, 64);
      const bfrag bv0 = ldfrag(VT, hk, ks * 32, 64);
      const bfrag bv1 = ldfrag(VT, hk + 16, ks * 32, 64);
      o0 = MFMA16(ap, bv0, o0);
      o1 = MFMA16(ap, bv1, o1);
    }
    #pragma unroll
    for (int reg = 0; reg < 4; ++reg) {
      const long orow = GROW(rbase + reg);
      O[orow * 256 + hk + colb] = (unsigned short)bf16b(o0[reg]);
      O[orow * 256 + hk + 16 + colb] = (unsigned short)bf16b(o1[reg]);
    }
  }
  #undef SROW
  #undef GROW
}

// ---- fused MLP v3: issue-early/wait-late pipelined staging ----
// Separate w1/w2 buffers; raw s_barrier + explicit waitcnt; 2 barriers/chunk.
// w2[ch] flies under GEMM1+GELU; w1[ch+1] flies under GEMM2.
// LDS 106496B: H2 32K | WSa(w1) 32K | WSb(w2) 32K | HD 8K  -> 1 block/CU, 8 waves
__global__ __launch_bounds__(512, 2) void swin_mlp(
    const float* __restrict__ x, const unsigned short* __restrict__ outw,
    const float* __restrict__ ln2g, const float* __restrict__ ln2b,
    const float* __restrict__ b1, const float* __restrict__ b2,
    float* __restrict__ y)
{
  __shared__ __align__(16) char smem[106496];
  char* H2  = smem;
  char* WSa = smem + 32768;
  char* WSb = smem + 65536;
  char* HD  = smem + 98304;
  const int t = threadIdx.x, wv = t >> 6, l = t & 63;
  const long base = (long)blockIdx.x << 6;

  const int mq = wv >> 1, nq = (wv & 1) << 1;
  const int c0 = mq * 16 + ((l >> 4) << 2);

  // prologue: issue chunk-0 stages + chunk-0 bias FIRST (fly under LN)
  glds_stage<512>(WSa, g_wt + 262144, 256, 32768);           // w1[0]
  float4 b14 = *(const float4*)(b1 + c0);                    // bias[0]
  glds_stage<128>(WSb, g_wt + 524288, 1024, 32768);          // w2[0]

  #pragma unroll
  for (int i = 0; i < 8; ++i) {
    const int r = wv * 8 + i;
    const uint2 raw = *(const uint2*)(outw + (base + r) * 256 + l * 4);
    unsigned o0, o1;
    ln_pack(bf2f(raw.x & 0xFFFFu), bf2f(raw.x >> 16), bf2f(raw.y & 0xFFFFu), bf2f(raw.y >> 16),
            ln2g, ln2b, l, o0, o1);
    *(unsigned*)(H2 + swz(r, l * 4, 256)) = o0;
    *(unsigned*)(H2 + swz(r, l * 4 + 2, 256)) = o1;
  }
  __syncthreads();   // full drain OK in prologue; w1[0]/w2[0] resident after this

  ffrag acc2[2][4];
  #pragma unroll
  for (int mt = 0; mt < 2; ++mt)
    #pragma unroll
    for (int nt = 0; nt < 4; ++nt) { ffrag z = {0.f, 0.f, 0.f, 0.f}; acc2[mt][nt] = z; }

  for (int ch = 0; ch < 16; ++ch) {
    // GEMM1: reads WSa (w1[ch]) + H2. (w2[ch] loads may still be in flight)
    ffrag a1[2];
    { ffrag z = {0.f, 0.f, 0.f, 0.f}; a1[0] = z; a1[1] = z; }
    #pragma unroll
    for (int ks = 0; ks < 8; ++ks) {
      const bfrag a = ldfrag(WSa, mq * 16, ks * 32, 256);
      const bfrag bb0 = ldfrag(H2, nq * 16, ks * 32, 256);
      const bfrag bb1 = ldfrag(H2, (nq + 1) * 16, ks * 32, 256);
      a1[0] = MFMA16(a, bb0, a1[0]);
      a1[1] = MFMA16(a, bb1, a1[1]);
    }
    // bias + GELU -> HD
    #pragma unroll
    for (int nt = 0; nt < 2; ++nt) {
      const int rr = (nq + nt) * 16 + (l & 15);
      const float g0 = gelu_f(a1[nt][0] + b14.x);
      const float g1 = gelu_f(a1[nt][1] + b14.y);
      const float g2 = gelu_f(a1[nt][2] + b14.z);
      const float g3 = gelu_f(a1[nt][3] + b14.w);
      *(unsigned*)(HD + swz(rr, c0, 64)) = pk2(g0, g1);
      *(unsigned*)(HD + swz(rr, c0 + 2, 64)) = pk2(g2, g3);
    }
    // barrier 1: my LDS ops done + my w2[ch] loads landed; join all waves.
    asm volatile("s_waitcnt vmcnt(0) lgkmcnt(0)" ::: "memory");
    __builtin_amdgcn_s_barrier();
    asm volatile("" ::: "memory");
    // issue w1[ch+1] -> WSa (flies under GEMM2)
    if (ch < 15) glds_stage<512>(WSa, g_wt + 262144 + (ch + 1) * 64 * 256, 256, 32768);

    // GEMM2: reads WSb (w2[ch]) + HD
    #pragma unroll
    for (int ks = 0; ks < 2; ++ks) {
      const bfrag am0 = ldfrag(WSb, (wv * 2) * 16, ks * 32, 64);
      const bfrag am1 = ldfrag(WSb, (wv * 2 + 1) * 16, ks * 32, 64);
      #pragma unroll
      for (int nt = 0; nt < 4; ++nt) {
        const bfrag bb = ldfrag(HD, nt * 16, ks * 32, 64);
        acc2[0][nt] = MFMA16(am0, bb, acc2[0][nt]);
        acc2[1][nt] = MFMA16(am1, bb, acc2[1][nt]);
      }
    }
    // barrier 2: my ds reads done + my w1[ch+1] loads landed; join all waves.
    asm volatile("s_waitcnt vmcnt(0) lgkmcnt(0)" ::: "memory");
    __builtin_amdgcn_s_barrier();
    asm volatile("" ::: "memory");
    // bias[ch+1] first (so its consumption leaves w2[ch+1] in flight), then w2[ch+1]
    if (ch < 15) {
      b14 = *(const float4*)(b1 + (ch + 1) * 64 + c0);
      glds_stage<128>(WSb, g_wt + 524288 + (ch + 1) * 64, 1024, 32768);
    }
  }

  #pragma unroll
  for (int mt = 0; mt < 2; ++mt) {
    const int cc0 = (wv * 2 + mt) * 16 + ((l >> 4) << 2);
    const float4 b24 = *(const float4*)(b2 + cc0);
    #pragma unroll
    for (int nt = 0; nt < 4; ++nt) {
      const long row = base + nt * 16 + (l & 15);
      const float4 xv = *(const float4*)(x + row * 256 + cc0);
      const uint2 ov = *(const uint2*)(outw + row * 256 + cc0);
      float4 res;
      res.x = acc2[mt][nt][0] + b24.x + xv.x + bf2f(ov.x & 0xFFFFu);
      res.y = acc2[mt][nt][1] + b24.y + xv.y + bf2f(ov.x >> 16);
      res.z = acc2[mt][nt][2] + b24.z + xv.z + bf2f(ov.y & 0xFFFFu);
      res.w = acc2[mt][nt][3] + b24.w + xv.w + bf2f(ov.y >> 16);
      *(float4*)(y + row * 256 + cc0) = res;
    }
  }
}

extern "C" void kernel_launch(void* const* d_in, const int* in_sizes, int n_in,
                              void* d_out, int out_size, void* d_ws, size_t ws_size,
                              hipStream_t stream) {
  (void)in_sizes; (void)n_in; (void)out_size; (void)ws_size;
  const float* x      = (const float*)d_in[0];
  const float* qkv_w  = (const float*)d_in[1];
  const float* qkv_b  = (const float*)d_in[2];
  const float* proj_w = (const float*)d_in[3];
  const float* proj_b = (const float*)d_in[4];
  const float* rpb    = (const float*)d_in[5];
  const float* ln1g   = (const float*)d_in[6];
  const float* ln1b   = (const float*)d_in[7];
  const float* ln2g   = (const float*)d_in[8];
  const float* ln2b   = (const float*)d_in[9];
  const float* w1     = (const float*)d_in[10];
  const float* b1     = (const float*)d_in[11];
  const float* w2     = (const float*)d_in[12];
  const float* b2     = (const float*)d_in[13];
  float* y = (float*)d_out;
  char* ws = (char*)d_ws;

  // Workspace (peak exactly 268,435,456 B):
  //   phase A (per 4-batch group): XB [0,32M) | QKV [32M,128M) | Obuf [128M,256M)
  //   phase B: outw bf16 [0,128M) over dead XB/QKV; Obuf consumed by proj.
  unsigned short* XB   = (unsigned short*)(ws);
  unsigned short* QKV  = (unsigned short*)(ws + 33554432);
  unsigned short* Obuf = (unsigned short*)(ws + 134217728);
  unsigned short* outw = (unsigned short*)(ws);

  hipLaunchKernelGGL(conv_w, dim3(1536), dim3(256), 0, stream, qkv_w, proj_w, w1, w2);
  for (int g = 0; g < 4; ++g) {
    hipLaunchKernelGGL(ln1_k, dim3(8192), dim3(512), 0, stream,
                       x, ln1g, ln1b, XB, (long)g * 65536);
    hipLaunchKernelGGL(gemm_qkv, dim3(512, 6), dim3(512), 0, stream, XB, qkv_b, QKV);
    hipLaunchKernelGGL(attn_core, dim3(1024), dim3(512), 0, stream, QKV, rpb, Obuf, g * 4);
  }
  hipLaunchKernelGGL(gemm_proj, dim3(2048, 2), dim3(512), 0, stream, Obuf, proj_b, outw);
  hipLaunchKernelGGL(swin_mlp, dim3(4096), dim3(512), 0, stream,
                     x, outw, ln2g, ln2b, b1, b2, y);
}

// Round 19
// 1193.803 us; speedup vs baseline: 1.0662x; 1.0662x over previous
//
#include <hip/hip_runtime.h>
#include <math.h>

typedef short bfrag __attribute__((ext_vector_type(8)));   // 8 bf16 (4 VGPR)
typedef float ffrag __attribute__((ext_vector_type(4)));   // 4 f32 accum

#define MFMA16(a, b, c) __builtin_amdgcn_mfma_f32_16x16x32_bf16((a), (b), (c), 0, 0, 0)

// Pre-transposed bf16 weights ([outcol][k] row-major), built once by conv_w.
// qkv @0 (768x256), proj @196608 (256x256), w1 @262144 (1024x256), w2 @524288 (256x1024)
__device__ __align__(16) unsigned short g_wt[786432];

__device__ __forceinline__ unsigned bf16b(float f) {   // fp32 -> bf16 bits, RNE
  unsigned u = __float_as_uint(f);
  return (u + 0x7FFFu + ((u >> 16) & 1u)) >> 16;
}
__device__ __forceinline__ unsigned pk2(float lo, float hi) {
  return bf16b(lo) | (bf16b(hi) << 16);
}
__device__ __forceinline__ float bf2f(unsigned u) {
  return __uint_as_float(u << 16);
}

__global__ void conv_w(const float* __restrict__ qkv_w, const float* __restrict__ proj_w,
                       const float* __restrict__ w1, const float* __restrict__ w2) {
  const int idx = blockIdx.x * 256 + threadIdx.x;   // 393216 (c,k2) pairs
  const float* src; int c, k2, C, K, ofs;
  if (idx < 98304)       { src = qkv_w;  C = 768;  K = 256;  c = idx % 768;  k2 = idx / 768;  ofs = 0; }
  else if (idx < 131072) { int i = idx - 98304;  src = proj_w; C = 256;  K = 256;  c = i % 256;  k2 = i / 256;  ofs = 196608; }
  else if (idx < 262144) { int i = idx - 131072; src = w1;     C = 1024; K = 256;  c = i % 1024; k2 = i / 1024; ofs = 262144; }
  else                   { int i = idx - 262144; src = w2;     C = 256;  K = 1024; c = i % 256;  k2 = i / 256;  ofs = 524288; }
  const float lo = src[(2 * k2) * C + c];
  const float hi = src[(2 * k2 + 1) * C + c];
  *(unsigned*)&g_wt[ofs + c * K + 2 * k2] = pk2(lo, hi);
}

// Byte offset into [*][C] bf16 LDS tile, XOR-swizzled per 16B slot (C>=64: 8 slots).
__device__ __forceinline__ int swz(int row, int col, int C) {
  return row * (C * 2) + ((((col >> 3) ^ (row & 7)) << 4) + ((col & 7) << 1));
}
__device__ __forceinline__ bfrag ldfrag(const char* lds, int outer, int k0, int C) {
  const int l = threadIdx.x & 63;
  return *(const bfrag*)(lds + swz(outer + (l & 15), k0 + ((l >> 4) << 3), C));
}

// Stage a [128][128] bf16 tile (32KB): linear LDS dest + inverse-swizzled source.
__device__ __forceinline__ void stage128(char* lds, const unsigned short* __restrict__ src,
                                         long rowBase, int strideShorts, int kOfs) {
  const int wv = threadIdx.x >> 6, l = threadIdx.x & 63;
  #pragma unroll
  for (int p = 0; p < 4; ++p) {
    const int base = wv * 1024 + p * 8192;
    const int off = base + l * 16;
    const int row = off >> 8;
    const int ss = ((off & 255) >> 4) ^ (row & 7);
    const unsigned short* g = src + (rowBase + row) * (long)strideShorts + kOfs + ss * 8;
    __builtin_amdgcn_global_load_lds((const __attribute__((address_space(1))) void*)g,
                                     (__attribute__((address_space(3))) void*)(lds + base),
                                     16, 0, 0);
  }
}

// Generic weight-tile stage. DSTROWB = LDS row bytes; slot-XOR mask 7 (matches swz).
template <int DSTROWB>
__device__ __forceinline__ void glds_stage(char* lds, const unsigned short* src,
                                           int srcRowShorts, int bytes) {
  const int wv = threadIdx.x >> 6, l = threadIdx.x & 63;
  for (int base = wv * 1024; base < bytes; base += 8192) {
    const int off = base + l * 16;
    const int row = off / DSTROWB;
    const int slot = (off % DSTROWB) >> 4;
    const int ss = slot ^ (row & 7);
    const unsigned short* g = src + row * srcRowShorts + ss * 8;
    __builtin_amdgcn_global_load_lds((const __attribute__((address_space(1))) void*)g,
                                     (__attribute__((address_space(3))) void*)(lds + base),
                                     16, 0, 0);
  }
}

// 128x128 tile core over one BK=128 chunk (C=128 LDS tiles), 4 k-steps.
__device__ __forceinline__ void mm_core128(const char* AX, const char* BW, ffrag acc[2][4]) {
  const int wv = threadIdx.x >> 6;
  const int rh = wv >> 2, cq = wv & 3;
  #pragma unroll
  for (int ks = 0; ks < 4; ++ks) {
    const bfrag aw0 = ldfrag(BW, cq * 32, ks * 32, 128);
    const bfrag aw1 = ldfrag(BW, cq * 32 + 16, ks * 32, 128);
    #pragma unroll
    for (int nt = 0; nt < 4; ++nt) {
      const bfrag xb = ldfrag(AX, rh * 64 + nt * 16, ks * 32, 128);
      acc[0][nt] = MFMA16(aw0, xb, acc[0][nt]);
      acc[1][nt] = MFMA16(aw1, xb, acc[1][nt]);
    }
  }
}

// Wave-per-row LayerNorm: 4 elems/lane in, two packed bf16 words out.
__device__ __forceinline__ void ln_pack(float d0, float d1, float d2, float d3,
                                        const float* g, const float* bb, int lane,
                                        unsigned& o0, unsigned& o1) {
  float s = d0 + d1 + d2 + d3;
  #pragma unroll
  for (int o = 32; o; o >>= 1) s += __shfl_xor(s, o);
  const float mu = s * (1.f / 256.f);
  d0 -= mu; d1 -= mu; d2 -= mu; d3 -= mu;
  float q = d0 * d0 + d1 * d1 + d2 * d2 + d3 * d3;
  #pragma unroll
  for (int o = 32; o; o >>= 1) q += __shfl_xor(q, o);
  const float vv = q * (1.f / 256.f) + 1e-5f;
  float rs = rsqrtf(vv);
  rs = rs * (1.5f - 0.5f * vv * rs * rs);
  const float4 g4 = *(const float4*)(g + lane * 4);
  const float4 b4 = *(const float4*)(bb + lane * 4);
  o0 = pk2(d0 * rs * g4.x + b4.x, d1 * rs * g4.y + b4.y);
  o1 = pk2(d2 * rs * g4.z + b4.z, d3 * rs * g4.w + b4.w);
}

// LN1 for one batch-group: 8192 blocks x 8 rows.
__global__ __launch_bounds__(512) void ln1_k(const float* __restrict__ x,
    const float* __restrict__ g, const float* __restrict__ bb,
    unsigned short* __restrict__ XB, long rowOfs) {
  const int wv = threadIdx.x >> 6, l = threadIdx.x & 63;
  const long lrow = (long)blockIdx.x * 8 + wv;
  const float4 v = *(const float4*)(x + (rowOfs + lrow) * 256 + l * 4);
  unsigned o0, o1;
  ln_pack(v.x, v.y, v.z, v.w, g, bb, l, o0, o1);
  unsigned short* dp = XB + lrow * 256 + l * 4;
  *(unsigned*)dp = o0; *(unsigned*)(dp + 2) = o1;
}

// qkv GEMM for one group: grid (512, 6). BK=128 x2, 64KB LDS, 2 blocks/CU.
__global__ __launch_bounds__(512, 4) void gemm_qkv(const unsigned short* __restrict__ XB,
    const float* __restrict__ qkv_b, unsigned short* __restrict__ QKV) {
  __shared__ __align__(16) char smem[65536];
  char* AX = smem; char* BW = smem + 32768;
  const int mb = blockIdx.x, nb = blockIdx.y;
  ffrag acc[2][4];
  #pragma unroll
  for (int a = 0; a < 2; ++a)
    #pragma unroll
    for (int n = 0; n < 4; ++n) { ffrag z = {0.f, 0.f, 0.f, 0.f}; acc[a][n] = z; }
  #pragma unroll
  for (int kc = 0; kc < 2; ++kc) {
    stage128(AX, XB, (long)mb * 128, 256, kc * 128);
    stage128(BW, g_wt, (long)nb * 128, 256, kc * 128);
    __syncthreads();
    mm_core128(AX, BW, acc);
    __syncthreads();
  }
  const int l = threadIdx.x & 63, wv = threadIdx.x >> 6;
  const int rh = wv >> 2, cq = wv & 3;
  const float sc = (nb < 2) ? 0.17677669529663687f : 1.f;   // Q pre-scale
  #pragma unroll
  for (int mt = 0; mt < 2; ++mt) {
    const int cg = nb * 128 + cq * 32 + mt * 16 + ((l >> 4) << 2);
    const float4 bq = *(const float4*)(qkv_b + cg);
    #pragma unroll
    for (int nt = 0; nt < 4; ++nt) {
      const long row = (long)mb * 128 + rh * 64 + nt * 16 + (l & 15);
      unsigned short* dp = QKV + row * 768 + cg;
      *(unsigned*)dp       = pk2((acc[mt][nt][0] + bq.x) * sc, (acc[mt][nt][1] + bq.y) * sc);
      *(unsigned*)(dp + 2) = pk2((acc[mt][nt][2] + bq.z) * sc, (acc[mt][nt][3] + bq.w) * sc);
    }
  }
}

// proj GEMM: full M=262144, grid (2048, 2). BK=128 x2, 2 blocks/CU.
__global__ __launch_bounds__(512, 4) void gemm_proj(const unsigned short* __restrict__ O,
    const float* __restrict__ proj_b, unsigned short* __restrict__ outw) {
  __shared__ __align__(16) char smem[65536];
  char* AX = smem; char* BW = smem + 32768;
  const int mb = blockIdx.x, nb = blockIdx.y;
  ffrag acc[2][4];
  #pragma unroll
  for (int a = 0; a < 2; ++a)
    #pragma unroll
    for (int n = 0; n < 4; ++n) { ffrag z = {0.f, 0.f, 0.f, 0.f}; acc[a][n] = z; }
  #pragma unroll
  for (int kc = 0; kc < 2; ++kc) {
    stage128(AX, O, (long)mb * 128, 256, kc * 128);
    stage128(BW, g_wt + 196608, (long)nb * 128, 256, kc * 128);
    __syncthreads();
    mm_core128(AX, BW, acc);
    __syncthreads();
  }
  const int l = threadIdx.x & 63, wv = threadIdx.x >> 6;
  const int rh = wv >> 2, cq = wv & 3;
  #pragma unroll
  for (int mt = 0; mt < 2; ++mt) {
    const int cg = nb * 128 + cq * 32 + mt * 16 + ((l >> 4) << 2);
    const float4 pb = *(const float4*)(proj_b + cg);
    #pragma unroll
    for (int nt = 0; nt < 4; ++nt) {
      const long row = (long)mb * 128 + rh * 64 + nt * 16 + (l & 15);
      unsigned short* dp = outw + row * 256 + cg;
      *(unsigned*)dp       = pk2(acc[mt][nt][0] + pb.x, acc[mt][nt][1] + pb.y);
      *(unsigned*)(dp + 2) = pk2(acc[mt][nt][2] + pb.z, acc[mt][nt][3] + pb.w);
    }
  }
}

// ---- attention core: one block per 8x8 window (1024 blocks/group) ----
// LDS 80KB: KL[64][256] 32K | VT[256][64] 32K | PB 8 x [16][64] 16K  -> 2 blocks/CU
__global__ __launch_bounds__(512, 4) void attn_core(const unsigned short* __restrict__ QKV,
    const float* __restrict__ rpb, unsigned short* __restrict__ O, int bofs) {
  __shared__ __align__(16) char smem[81920];
  char* KL = smem;
  char* VT = smem + 32768;
  char* PB = smem + 65536;
  const int t = threadIdx.x, wv = t >> 6, l = t & 63;
  const int blk = blockIdx.x;
  const int b = blk >> 8, w = blk & 255;   // b = local batch 0..3
  const int wi = w >> 4, wj = w & 15;
  const int bi0 = wi * 8 + 4, bj0 = wj * 8 + 4;
  const ffrag ZERO4 = {0.f, 0.f, 0.f, 0.f};

  #define SROW(r) (((long)b << 14) + (((bi0 + ((r) >> 3)) & 127) << 7) + ((bj0 + ((r) & 7)) & 127))
  #define GROW(r) (((long)(bofs + b) << 14) + (((bi0 + ((r) >> 3)) & 127) << 7) + ((bj0 + ((r) & 7)) & 127))

  // stage K rows -> KL (swizzled via pre-swizzled source)
  #pragma unroll
  for (int p = 0; p < 4; ++p) {
    const int base = wv * 1024 + p * 8192;
    const int off = base + l * 16;
    const int kv = off >> 9;
    const int ss = ((off & 511) >> 4) ^ (kv & 7);
    const unsigned short* g = QKV + SROW(kv) * 768 + 256 + ss * 8;
    __builtin_amdgcn_global_load_lds((const __attribute__((address_space(1))) void*)g,
                                     (__attribute__((address_space(3))) void*)(KL + base),
                                     16, 0, 0);
  }

  // stage V -> VT transposed (packed b32 writes)
  {
    const int rp = t & 31, dh = t >> 5;              // row-pair, d-hextet
    const unsigned short* v0p = QKV + SROW(2 * rp) * 768 + 512 + dh * 16;
    const unsigned short* v1p = QKV + SROW(2 * rp + 1) * 768 + 512 + dh * 16;
    const bfrag a0 = *(const bfrag*)v0p, a1 = *(const bfrag*)(v0p + 8);
    const bfrag c0 = *(const bfrag*)v1p, c1 = *(const bfrag*)(v1p + 8);
    #pragma unroll
    for (int j = 0; j < 8; ++j) {
      const unsigned w0 = ((unsigned)(unsigned short)a0[j]) | (((unsigned)(unsigned short)c0[j]) << 16);
      const unsigned w1 = ((unsigned)(unsigned short)a1[j]) | (((unsigned)(unsigned short)c1[j]) << 16);
      *(unsigned*)(VT + swz(dh * 16 + j, 2 * rp, 64)) = w0;
      *(unsigned*)(VT + swz(dh * 16 + 8 + j, 2 * rp, 64)) = w1;
    }
  }
  __syncthreads();

  const int qt = wv & 3, hh = wv >> 2;
  char* myPB = PB + wv * 2048;
  const int colb = l & 15;
  const int rbase = qt * 16 + ((l >> 4) << 2);

  for (int i = 0; i < 4; ++i) {
    const int h = 2 * i + hh;
    const int hk = h * 32;
    const int qr = qt * 16 + (l & 15);
    const bfrag aq = *(const bfrag*)(QKV + SROW(qr) * 768 + hk + ((l >> 4) << 3));
    ffrag s[4];
    #pragma unroll
    for (int nt = 0; nt < 4; ++nt) {
      const bfrag bk = ldfrag(KL, nt * 16, hk, 256);
      s[nt] = MFMA16(aq, bk, ZERO4);
    }
    float pr[4][4], mx[4], sm[4];
    #pragma unroll
    for (int reg = 0; reg < 4; ++reg) mx[reg] = -3e38f;
    #pragma unroll
    for (int nt = 0; nt < 4; ++nt)
      #pragma unroll
      for (int reg = 0; reg < 4; ++reg) {
        const int rr = rbase + reg, cc = nt * 16 + colb;
        const int idx = ((rr >> 3) - (cc >> 3) + 7) * 15 + ((rr & 7) - (cc & 7) + 7);
        pr[nt][reg] = s[nt][reg] + rpb[idx * 8 + h];
        mx[reg] = fmaxf(mx[reg], pr[nt][reg]);
      }
    #pragma unroll
    for (int reg = 0; reg < 4; ++reg) {
      #pragma unroll
      for (int o = 1; o < 16; o <<= 1) mx[reg] = fmaxf(mx[reg], __shfl_xor(mx[reg], o));
      sm[reg] = 0.f;
    }
    #pragma unroll
    for (int nt = 0; nt < 4; ++nt)
      #pragma unroll
      for (int reg = 0; reg < 4; ++reg) {
        pr[nt][reg] = __expf(pr[nt][reg] - mx[reg]);
        sm[reg] += pr[nt][reg];
      }
    #pragma unroll
    for (int reg = 0; reg < 4; ++reg) {
      #pragma unroll
      for (int o = 1; o < 16; o <<= 1) sm[reg] += __shfl_xor(sm[reg], o);
      sm[reg] = 1.f / sm[reg];
    }
    #pragma unroll
    for (int nt = 0; nt < 4; ++nt)
      #pragma unroll
      for (int reg = 0; reg < 4; ++reg)
        *(unsigned short*)(myPB + swz(((l >> 4) << 2) + reg, nt * 16 + colb, 64)) =
            (unsigned short)bf16b(pr[nt][reg] * sm[reg]);

    ffrag o0 = ZERO4, o1 = ZERO4;
    #pragma unroll
    for (int ks = 0; ks < 2; ++ks) {
      const bfrag ap = ldfrag(myPB, 0, ks * 32, 64);
      const bfrag bv0 = ldfrag(VT, hk, ks * 32, 64);
      const bfrag bv1 = ldfrag(VT, hk + 16, ks * 32, 64);
      o0 = MFMA16(ap, bv0, o0);
      o1 = MFMA16(ap, bv1, o1);
    }
    #pragma unroll
    for (int reg = 0; reg < 4; ++reg) {
      const long orow = GROW(rbase + reg);
      O[orow * 256 + hk + colb] = (unsigned short)bf16b(o0[reg]);
      O[orow * 256 + hk + 16 + colb] = (unsigned short)bf16b(o1[reg]);
    }
  }
  #undef SROW
  #undef GROW
}

// ---- fused MLP: R13-measured-best config (649us, reproduced twice). 64-col
// staged chunks, erff GELU, GELU->store then w2-stage order. 2 blk/CU.
// LDS 73728B: H2[64][256] 32K | WS 32K (w1 [64][256] / w2 [256][64]) | HD[64][64] 8K
__global__ __launch_bounds__(512, 4) void swin_mlp(
    const float* __restrict__ x, const unsigned short* __restrict__ outw,
    const float* __restrict__ ln2g, const float* __restrict__ ln2b,
    const float* __restrict__ b1, const float* __restrict__ b2,
    float* __restrict__ y)
{
  __shared__ __align__(16) char smem[73728];
  char* H2 = smem;
  char* WS = smem + 32768;
  char* HD = smem + 65536;
  const int t = threadIdx.x, wv = t >> 6, l = t & 63;
  const long base = (long)blockIdx.x << 6;

  #pragma unroll
  for (int i = 0; i < 8; ++i) {
    const int r = wv * 8 + i;
    const uint2 raw = *(const uint2*)(outw + (base + r) * 256 + l * 4);
    unsigned o0, o1;
    ln_pack(bf2f(raw.x & 0xFFFFu), bf2f(raw.x >> 16), bf2f(raw.y & 0xFFFFu), bf2f(raw.y >> 16),
            ln2g, ln2b, l, o0, o1);
    *(unsigned*)(H2 + swz(r, l * 4, 256)) = o0;
    *(unsigned*)(H2 + swz(r, l * 4 + 2, 256)) = o1;
  }
  __syncthreads();

  const int mq = wv >> 1, nq = (wv & 1) << 1;

  ffrag acc2[2][4];
  #pragma unroll
  for (int mt = 0; mt < 2; ++mt)
    #pragma unroll
    for (int nt = 0; nt < 4; ++nt) { ffrag z = {0.f, 0.f, 0.f, 0.f}; acc2[mt][nt] = z; }

  for (int ch = 0; ch < 16; ++ch) {
    glds_stage<512>(WS, g_wt + 262144 + ch * 64 * 256, 256, 32768);
    __syncthreads();
    ffrag a1[2];
    { ffrag z = {0.f, 0.f, 0.f, 0.f}; a1[0] = z; a1[1] = z; }
    #pragma unroll
    for (int ks = 0; ks < 8; ++ks) {
      const bfrag a = ldfrag(WS, mq * 16, ks * 32, 256);
      const bfrag bb0 = ldfrag(H2, nq * 16, ks * 32, 256);
      const bfrag bb1 = ldfrag(H2, (nq + 1) * 16, ks * 32, 256);
      a1[0] = MFMA16(a, bb0, a1[0]);
      a1[1] = MFMA16(a, bb1, a1[1]);
    }
    __syncthreads();   // WS(w1) reads done

    // bias + exact GELU -> HD; then stage w2 chunk [256 outcols][64 k]
    const int c0 = mq * 16 + ((l >> 4) << 2);
    const float4 b14 = *(const float4*)(b1 + ch * 64 + c0);
    #pragma unroll
    for (int nt = 0; nt < 2; ++nt) {
      const int rr = (nq + nt) * 16 + (l & 15);
      const float u0 = a1[nt][0] + b14.x, u1 = a1[nt][1] + b14.y;
      const float u2 = a1[nt][2] + b14.z, u3 = a1[nt][3] + b14.w;
      const float g0 = 0.5f * u0 * (1.f + erff(u0 * 0.70710678118654752f));
      const float g1 = 0.5f * u1 * (1.f + erff(u1 * 0.70710678118654752f));
      const float g2 = 0.5f * u2 * (1.f + erff(u2 * 0.70710678118654752f));
      const float g3 = 0.5f * u3 * (1.f + erff(u3 * 0.70710678118654752f));
      *(unsigned*)(HD + swz(rr, c0, 64)) = pk2(g0, g1);
      *(unsigned*)(HD + swz(rr, c0 + 2, 64)) = pk2(g2, g3);
    }
    glds_stage<128>(WS, g_wt + 524288 + ch * 64, 1024, 32768);
    __syncthreads();

    // GEMM2: wave handles outcols wv*32..+31 (m-tiles 2wv, 2wv+1), all 4 n-tiles
    #pragma unroll
    for (int ks = 0; ks < 2; ++ks) {
      const bfrag am0 = ldfrag(WS, (wv * 2) * 16, ks * 32, 64);
      const bfrag am1 = ldfrag(WS, (wv * 2 + 1) * 16, ks * 32, 64);
      #pragma unroll
      for (int nt = 0; nt < 4; ++nt) {
        const bfrag bb = ldfrag(HD, nt * 16, ks * 32, 64);
        acc2[0][nt] = MFMA16(am0, bb, acc2[0][nt]);
        acc2[1][nt] = MFMA16(am1, bb, acc2[1][nt]);
      }
    }
    __syncthreads();   // WS/HD reads done before next chunk
  }

  #pragma unroll
  for (int mt = 0; mt < 2; ++mt) {
    const int c0 = (wv * 2 + mt) * 16 + ((l >> 4) << 2);
    const float4 b24 = *(const float4*)(b2 + c0);
    #pragma unroll
    for (int nt = 0; nt < 4; ++nt) {
      const long row = base + nt * 16 + (l & 15);
      const float4 xv = *(const float4*)(x + row * 256 + c0);
      const uint2 ov = *(const uint2*)(outw + row * 256 + c0);
      float4 res;
      res.x = acc2[mt][nt][0] + b24.x + xv.x + bf2f(ov.x & 0xFFFFu);
      res.y = acc2[mt][nt][1] + b24.y + xv.y + bf2f(ov.x >> 16);
      res.z = acc2[mt][nt][2] + b24.z + xv.z + bf2f(ov.y & 0xFFFFu);
      res.w = acc2[mt][nt][3] + b24.w + xv.w + bf2f(ov.y >> 16);
      *(float4*)(y + row * 256 + c0) = res;
    }
  }
}

extern "C" void kernel_launch(void* const* d_in, const int* in_sizes, int n_in,
                              void* d_out, int out_size, void* d_ws, size_t ws_size,
                              hipStream_t stream) {
  (void)in_sizes; (void)n_in; (void)out_size; (void)ws_size;
  const float* x      = (const float*)d_in[0];
  const float* qkv_w  = (const float*)d_in[1];
  const float* qkv_b  = (const float*)d_in[2];
  const float* proj_w = (const float*)d_in[3];
  const float* proj_b = (const float*)d_in[4];
  const float* rpb    = (const float*)d_in[5];
  const float* ln1g   = (const float*)d_in[6];
  const float* ln1b   = (const float*)d_in[7];
  const float* ln2g   = (const float*)d_in[8];
  const float* ln2b   = (const float*)d_in[9];
  const float* w1     = (const float*)d_in[10];
  const float* b1     = (const float*)d_in[11];
  const float* w2     = (const float*)d_in[12];
  const float* b2     = (const float*)d_in[13];
  float* y = (float*)d_out;
  char* ws = (char*)d_ws;

  // Workspace (peak exactly 268,435,456 B):
  //   phase A (per 4-batch group): XB [0,32M) | QKV [32M,128M) | Obuf [128M,256M)
  //   phase B: outw bf16 [0,128M) over dead XB/QKV; Obuf consumed by proj.
  unsigned short* XB   = (unsigned short*)(ws);
  unsigned short* QKV  = (unsigned short*)(ws + 33554432);
  unsigned short* Obuf = (unsigned short*)(ws + 134217728);
  unsigned short* outw = (unsigned short*)(ws);

  hipLaunchKernelGGL(conv_w, dim3(1536), dim3(256), 0, stream, qkv_w, proj_w, w1, w2);
  for (int g = 0; g < 4; ++g) {
    hipLaunchKernelGGL(ln1_k, dim3(8192), dim3(512), 0, stream,
                       x, ln1g, ln1b, XB, (long)g * 65536);
    hipLaunchKernelGGL(gemm_qkv, dim3(512, 6), dim3(512), 0, stream, XB, qkv_b, QKV);
    hipLaunchKernelGGL(attn_core, dim3(1024), dim3(512), 0, stream, QKV, rpb, Obuf, g * 4);
  }
  hipLaunchKernelGGL(gemm_proj, dim3(2048, 2), dim3(512), 0, stream, Obuf, proj_b, outw);
  hipLaunchKernelGGL(swin_mlp, dim3(4096), dim3(512), 0, stream,
                     x, outw, ln2g, ln2b, b1, b2, y);
}

// Round 20
// 1191.470 us; speedup vs baseline: 1.0683x; 1.0020x over previous
//
#include <hip/hip_runtime.h>
#include <math.h>

typedef short bfrag __attribute__((ext_vector_type(8)));   // 8 bf16 (4 VGPR)
typedef float ffrag __attribute__((ext_vector_type(4)));   // 4 f32 accum

#define MFMA16(a, b, c) __builtin_amdgcn_mfma_f32_16x16x32_bf16((a), (b), (c), 0, 0, 0)

// Pre-transposed bf16 weights ([outcol][k] row-major), built once by conv_w.
// qkv @0 (768x256), proj @196608 (256x256), w1 @262144 (1024x256), w2 @524288 (256x1024)
__device__ __align__(16) unsigned short g_wt[786432];

__device__ __forceinline__ unsigned bf16b(float f) {   // fp32 -> bf16 bits, RNE
  unsigned u = __float_as_uint(f);
  return (u + 0x7FFFu + ((u >> 16) & 1u)) >> 16;
}
__device__ __forceinline__ unsigned pk2(float lo, float hi) {
  return bf16b(lo) | (bf16b(hi) << 16);
}
__device__ __forceinline__ float bf2f(unsigned u) {
  return __uint_as_float(u << 16);
}

__global__ void conv_w(const float* __restrict__ qkv_w, const float* __restrict__ proj_w,
                       const float* __restrict__ w1, const float* __restrict__ w2) {
  const int idx = blockIdx.x * 256 + threadIdx.x;   // 393216 (c,k2) pairs
  const float* src; int c, k2, C, K, ofs;
  if (idx < 98304)       { src = qkv_w;  C = 768;  K = 256;  c = idx % 768;  k2 = idx / 768;  ofs = 0; }
  else if (idx < 131072) { int i = idx - 98304;  src = proj_w; C = 256;  K = 256;  c = i % 256;  k2 = i / 256;  ofs = 196608; }
  else if (idx < 262144) { int i = idx - 131072; src = w1;     C = 1024; K = 256;  c = i % 1024; k2 = i / 1024; ofs = 262144; }
  else                   { int i = idx - 262144; src = w2;     C = 256;  K = 1024; c = i % 256;  k2 = i / 256;  ofs = 524288; }
  const float lo = src[(2 * k2) * C + c];
  const float hi = src[(2 * k2 + 1) * C + c];
  *(unsigned*)&g_wt[ofs + c * K + 2 * k2] = pk2(lo, hi);
}

// Byte offset into [*][C] bf16 LDS tile, XOR-swizzled per 16B slot (C>=64: 8 slots).
__device__ __forceinline__ int swz(int row, int col, int C) {
  return row * (C * 2) + ((((col >> 3) ^ (row & 7)) << 4) + ((col & 7) << 1));
}
__device__ __forceinline__ bfrag ldfrag(const char* lds, int outer, int k0, int C) {
  const int l = threadIdx.x & 63;
  return *(const bfrag*)(lds + swz(outer + (l & 15), k0 + ((l >> 4) << 3), C));
}

// Stage a [128][128] bf16 tile (32KB): linear LDS dest + inverse-swizzled source.
__device__ __forceinline__ void stage128(char* lds, const unsigned short* __restrict__ src,
                                         long rowBase, int strideShorts, int kOfs) {
  const int wv = threadIdx.x >> 6, l = threadIdx.x & 63;
  #pragma unroll
  for (int p = 0; p < 4; ++p) {
    const int base = wv * 1024 + p * 8192;
    const int off = base + l * 16;
    const int row = off >> 8;
    const int ss = ((off & 255) >> 4) ^ (row & 7);
    const unsigned short* g = src + (rowBase + row) * (long)strideShorts + kOfs + ss * 8;
    __builtin_amdgcn_global_load_lds((const __attribute__((address_space(1))) void*)g,
                                     (__attribute__((address_space(3))) void*)(lds + base),
                                     16, 0, 0);
  }
}

// Generic weight-tile stage. DSTROWB = LDS row bytes; slot-XOR mask 7 (matches swz).
template <int DSTROWB>
__device__ __forceinline__ void glds_stage(char* lds, const unsigned short* src,
                                           int srcRowShorts, int bytes) {
  const int wv = threadIdx.x >> 6, l = threadIdx.x & 63;
  for (int base = wv * 1024; base < bytes; base += 8192) {
    const int off = base + l * 16;
    const int row = off / DSTROWB;
    const int slot = (off % DSTROWB) >> 4;
    const int ss = slot ^ (row & 7);
    const unsigned short* g = src + row * srcRowShorts + ss * 8;
    __builtin_amdgcn_global_load_lds((const __attribute__((address_space(1))) void*)g,
                                     (__attribute__((address_space(3))) void*)(lds + base),
                                     16, 0, 0);
  }
}

// 128x128 tile core over one BK=128 chunk (C=128 LDS tiles), 4 k-steps.
__device__ __forceinline__ void mm_core128(const char* AX, const char* BW, ffrag acc[2][4]) {
  const int wv = threadIdx.x >> 6;
  const int rh = wv >> 2, cq = wv & 3;
  #pragma unroll
  for (int ks = 0; ks < 4; ++ks) {
    const bfrag aw0 = ldfrag(BW, cq * 32, ks * 32, 128);
    const bfrag aw1 = ldfrag(BW, cq * 32 + 16, ks * 32, 128);
    #pragma unroll
    for (int nt = 0; nt < 4; ++nt) {
      const bfrag xb = ldfrag(AX, rh * 64 + nt * 16, ks * 32, 128);
      acc[0][nt] = MFMA16(aw0, xb, acc[0][nt]);
      acc[1][nt] = MFMA16(aw1, xb, acc[1][nt]);
    }
  }
}

// Wave-per-row LayerNorm: 4 elems/lane in, two packed bf16 words out.
__device__ __forceinline__ void ln_pack(float d0, float d1, float d2, float d3,
                                        const float* g, const float* bb, int lane,
                                        unsigned& o0, unsigned& o1) {
  float s = d0 + d1 + d2 + d3;
  #pragma unroll
  for (int o = 32; o; o >>= 1) s += __shfl_xor(s, o);
  const float mu = s * (1.f / 256.f);
  d0 -= mu; d1 -= mu; d2 -= mu; d3 -= mu;
  float q = d0 * d0 + d1 * d1 + d2 * d2 + d3 * d3;
  #pragma unroll
  for (int o = 32; o; o >>= 1) q += __shfl_xor(q, o);
  const float vv = q * (1.f / 256.f) + 1e-5f;
  float rs = rsqrtf(vv);
  rs = rs * (1.5f - 0.5f * vv * rs * rs);
  const float4 g4 = *(const float4*)(g + lane * 4);
  const float4 b4 = *(const float4*)(bb + lane * 4);
  o0 = pk2(d0 * rs * g4.x + b4.x, d1 * rs * g4.y + b4.y);
  o1 = pk2(d2 * rs * g4.z + b4.z, d3 * rs * g4.w + b4.w);
}

// LN1 for one batch-group: 8192 blocks x 8 rows.
__global__ __launch_bounds__(512) void ln1_k(const float* __restrict__ x,
    const float* __restrict__ g, const float* __restrict__ bb,
    unsigned short* __restrict__ XB, long rowOfs) {
  const int wv = threadIdx.x >> 6, l = threadIdx.x & 63;
  const long lrow = (long)blockIdx.x * 8 + wv;
  const float4 v = *(const float4*)(x + (rowOfs + lrow) * 256 + l * 4);
  unsigned o0, o1;
  ln_pack(v.x, v.y, v.z, v.w, g, bb, l, o0, o1);
  unsigned short* dp = XB + lrow * 256 + l * 4;
  *(unsigned*)dp = o0; *(unsigned*)(dp + 2) = o1;
}

// qkv GEMM for one group: grid (512, 6). BK=128 x2, 64KB LDS, 2 blocks/CU.
__global__ __launch_bounds__(512, 4) void gemm_qkv(const unsigned short* __restrict__ XB,
    const float* __restrict__ qkv_b, unsigned short* __restrict__ QKV) {
  __shared__ __align__(16) char smem[65536];
  char* AX = smem; char* BW = smem + 32768;
  const int mb = blockIdx.x, nb = blockIdx.y;
  ffrag acc[2][4];
  #pragma unroll
  for (int a = 0; a < 2; ++a)
    #pragma unroll
    for (int n = 0; n < 4; ++n) { ffrag z = {0.f, 0.f, 0.f, 0.f}; acc[a][n] = z; }
  #pragma unroll
  for (int kc = 0; kc < 2; ++kc) {
    stage128(AX, XB, (long)mb * 128, 256, kc * 128);
    stage128(BW, g_wt, (long)nb * 128, 256, kc * 128);
    __syncthreads();
    mm_core128(AX, BW, acc);
    __syncthreads();
  }
  const int l = threadIdx.x & 63, wv = threadIdx.x >> 6;
  const int rh = wv >> 2, cq = wv & 3;
  const float sc = (nb < 2) ? 0.17677669529663687f : 1.f;   // Q pre-scale
  #pragma unroll
  for (int mt = 0; mt < 2; ++mt) {
    const int cg = nb * 128 + cq * 32 + mt * 16 + ((l >> 4) << 2);
    const float4 bq = *(const float4*)(qkv_b + cg);
    #pragma unroll
    for (int nt = 0; nt < 4; ++nt) {
      const long row = (long)mb * 128 + rh * 64 + nt * 16 + (l & 15);
      unsigned short* dp = QKV + row * 768 + cg;
      *(unsigned*)dp       = pk2((acc[mt][nt][0] + bq.x) * sc, (acc[mt][nt][1] + bq.y) * sc);
      *(unsigned*)(dp + 2) = pk2((acc[mt][nt][2] + bq.z) * sc, (acc[mt][nt][3] + bq.w) * sc);
    }
  }
}

// proj GEMM: full M=262144, grid (2048, 2). BK=128 x2, 2 blocks/CU.
__global__ __launch_bounds__(512, 4) void gemm_proj(const unsigned short* __restrict__ O,
    const float* __restrict__ proj_b, unsigned short* __restrict__ outw) {
  __shared__ __align__(16) char smem[65536];
  char* AX = smem; char* BW = smem + 32768;
  const int mb = blockIdx.x, nb = blockIdx.y;
  ffrag acc[2][4];
  #pragma unroll
  for (int a = 0; a < 2; ++a)
    #pragma unroll
    for (int n = 0; n < 4; ++n) { ffrag z = {0.f, 0.f, 0.f, 0.f}; acc[a][n] = z; }
  #pragma unroll
  for (int kc = 0; kc < 2; ++kc) {
    stage128(AX, O, (long)mb * 128, 256, kc * 128);
    stage128(BW, g_wt + 196608, (long)nb * 128, 256, kc * 128);
    __syncthreads();
    mm_core128(AX, BW, acc);
    __syncthreads();
  }
  const int l = threadIdx.x & 63, wv = threadIdx.x >> 6;
  const int rh = wv >> 2, cq = wv & 3;
  #pragma unroll
  for (int mt = 0; mt < 2; ++mt) {
    const int cg = nb * 128 + cq * 32 + mt * 16 + ((l >> 4) << 2);
    const float4 pb = *(const float4*)(proj_b + cg);
    #pragma unroll
    for (int nt = 0; nt < 4; ++nt) {
      const long row = (long)mb * 128 + rh * 64 + nt * 16 + (l & 15);
      unsigned short* dp = outw + row * 256 + cg;
      *(unsigned*)dp       = pk2(acc[mt][nt][0] + pb.x, acc[mt][nt][1] + pb.y);
      *(unsigned*)(dp + 2) = pk2(acc[mt][nt][2] + pb.z, acc[mt][nt][3] + pb.w);
    }
  }
}

// ---- attention core: one block per 8x8 window (1024 blocks/group) ----
// LDS 80KB: KL[64][256] 32K | VT[256][64] 32K | PB 8 x [16][64] 16K  -> 2 blocks/CU
__global__ __launch_bounds__(512, 4) void attn_core(const unsigned short* __restrict__ QKV,
    const float* __restrict__ rpb, unsigned short* __restrict__ O, int bofs) {
  __shared__ __align__(16) char smem[81920];
  char* KL = smem;
  char* VT = smem + 32768;
  char* PB = smem + 65536;
  const int t = threadIdx.x, wv = t >> 6, l = t & 63;
  const int blk = blockIdx.x;
  const int b = blk >> 8, w = blk & 255;   // b = local batch 0..3
  const int wi = w >> 4, wj = w & 15;
  const int bi0 = wi * 8 + 4, bj0 = wj * 8 + 4;
  const ffrag ZERO4 = {0.f, 0.f, 0.f, 0.f};

  #define SROW(r) (((long)b << 14) + (((bi0 + ((r) >> 3)) & 127) << 7) + ((bj0 + ((r) & 7)) & 127))
  #define GROW(r) (((long)(bofs + b) << 14) + (((bi0 + ((r) >> 3)) & 127) << 7) + ((bj0 + ((r) & 7)) & 127))

  // stage K rows -> KL (swizzled via pre-swizzled source)
  #pragma unroll
  for (int p = 0; p < 4; ++p) {
    const int base = wv * 1024 + p * 8192;
    const int off = base + l * 16;
    const int kv = off >> 9;
    const int ss = ((off & 511) >> 4) ^ (kv & 7);
    const unsigned short* g = QKV + SROW(kv) * 768 + 256 + ss * 8;
    __builtin_amdgcn_global_load_lds((const __attribute__((address_space(1))) void*)g,
                                     (__attribute__((address_space(3))) void*)(KL + base),
                                     16, 0, 0);
  }

  // stage V -> VT transposed (packed b32 writes)
  {
    const int rp = t & 31, dh = t >> 5;              // row-pair, d-hextet
    const unsigned short* v0p = QKV + SROW(2 * rp) * 768 + 512 + dh * 16;
    const unsigned short* v1p = QKV + SROW(2 * rp + 1) * 768 + 512 + dh * 16;
    const bfrag a0 = *(const bfrag*)v0p, a1 = *(const bfrag*)(v0p + 8);
    const bfrag c0 = *(const bfrag*)v1p, c1 = *(const bfrag*)(v1p + 8);
    #pragma unroll
    for (int j = 0; j < 8; ++j) {
      const unsigned w0 = ((unsigned)(unsigned short)a0[j]) | (((unsigned)(unsigned short)c0[j]) << 16);
      const unsigned w1 = ((unsigned)(unsigned short)a1[j]) | (((unsigned)(unsigned short)c1[j]) << 16);
      *(unsigned*)(VT + swz(dh * 16 + j, 2 * rp, 64)) = w0;
      *(unsigned*)(VT + swz(dh * 16 + 8 + j, 2 * rp, 64)) = w1;
    }
  }
  __syncthreads();

  const int qt = wv & 3, hh = wv >> 2;
  char* myPB = PB + wv * 2048;
  const int colb = l & 15;
  const int rbase = qt * 16 + ((l >> 4) << 2);

  for (int i = 0; i < 4; ++i) {
    const int h = 2 * i + hh;
    const int hk = h * 32;
    const int qr = qt * 16 + (l & 15);
    const bfrag aq = *(const bfrag*)(QKV + SROW(qr) * 768 + hk + ((l >> 4) << 3));
    ffrag s[4];
    #pragma unroll
    for (int nt = 0; nt < 4; ++nt) {
      const bfrag bk = ldfrag(KL, nt * 16, hk, 256);
      s[nt] = MFMA16(aq, bk, ZERO4);
    }
    float pr[4][4], mx[4], sm[4];
    #pragma unroll
    for (int reg = 0; reg < 4; ++reg) mx[reg] = -3e38f;
    #pragma unroll
    for (int nt = 0; nt < 4; ++nt)
      #pragma unroll
      for (int reg = 0; reg < 4; ++reg) {
        const int rr = rbase + reg, cc = nt * 16 + colb;
        const int idx = ((rr >> 3) - (cc >> 3) + 7) * 15 + ((rr & 7) - (cc & 7) + 7);
        pr[nt][reg] = s[nt][reg] + rpb[idx * 8 + h];
        mx[reg] = fmaxf(mx[reg], pr[nt][reg]);
      }
    #pragma unroll
    for (int reg = 0; reg < 4; ++reg) {
      #pragma unroll
      for (int o = 1; o < 16; o <<= 1) mx[reg] = fmaxf(mx[reg], __shfl_xor(mx[reg], o));
      sm[reg] = 0.f;
    }
    #pragma unroll
    for (int nt = 0; nt < 4; ++nt)
      #pragma unroll
      for (int reg = 0; reg < 4; ++reg) {
        pr[nt][reg] = __expf(pr[nt][reg] - mx[reg]);
        sm[reg] += pr[nt][reg];
      }
    #pragma unroll
    for (int reg = 0; reg < 4; ++reg) {
      #pragma unroll
      for (int o = 1; o < 16; o <<= 1) sm[reg] += __shfl_xor(sm[reg], o);
      sm[reg] = 1.f / sm[reg];
    }
    #pragma unroll
    for (int nt = 0; nt < 4; ++nt)
      #pragma unroll
      for (int reg = 0; reg < 4; ++reg)
        *(unsigned short*)(myPB + swz(((l >> 4) << 2) + reg, nt * 16 + colb, 64)) =
            (unsigned short)bf16b(pr[nt][reg] * sm[reg]);

    ffrag o0 = ZERO4, o1 = ZERO4;
    #pragma unroll
    for (int ks = 0; ks < 2; ++ks) {
      const bfrag ap = ldfrag(myPB, 0, ks * 32, 64);
      const bfrag bv0 = ldfrag(VT, hk, ks * 32, 64);
      const bfrag bv1 = ldfrag(VT, hk + 16, ks * 32, 64);
      o0 = MFMA16(ap, bv0, o0);
      o1 = MFMA16(ap, bv1, o1);
    }
    #pragma unroll
    for (int reg = 0; reg < 4; ++reg) {
      const long orow = GROW(rbase + reg);
      O[orow * 256 + hk + colb] = (unsigned short)bf16b(o0[reg]);
      O[orow * 256 + hk + 16 + colb] = (unsigned short)bf16b(o1[reg]);
    }
  }
  #undef SROW
  #undef GROW
}

// ---- fused MLP: R13-measured-best config (reproduced 3x at 1193us total).
// 64-col staged chunks, erff GELU, GELU->store then w2-stage order. 2 blk/CU.
// LDS 73728B: H2[64][256] 32K | WS 32K (w1 [64][256] / w2 [256][64]) | HD[64][64] 8K
__global__ __launch_bounds__(512, 4) void swin_mlp(
    const float* __restrict__ x, const unsigned short* __restrict__ outw,
    const float* __restrict__ ln2g, const float* __restrict__ ln2b,
    const float* __restrict__ b1, const float* __restrict__ b2,
    float* __restrict__ y)
{
  __shared__ __align__(16) char smem[73728];
  char* H2 = smem;
  char* WS = smem + 32768;
  char* HD = smem + 65536;
  const int t = threadIdx.x, wv = t >> 6, l = t & 63;
  const long base = (long)blockIdx.x << 6;

  #pragma unroll
  for (int i = 0; i < 8; ++i) {
    const int r = wv * 8 + i;
    const uint2 raw = *(const uint2*)(outw + (base + r) * 256 + l * 4);
    unsigned o0, o1;
    ln_pack(bf2f(raw.x & 0xFFFFu), bf2f(raw.x >> 16), bf2f(raw.y & 0xFFFFu), bf2f(raw.y >> 16),
            ln2g, ln2b, l, o0, o1);
    *(unsigned*)(H2 + swz(r, l * 4, 256)) = o0;
    *(unsigned*)(H2 + swz(r, l * 4 + 2, 256)) = o1;
  }
  __syncthreads();

  const int mq = wv >> 1, nq = (wv & 1) << 1;

  ffrag acc2[2][4];
  #pragma unroll
  for (int mt = 0; mt < 2; ++mt)
    #pragma unroll
    for (int nt = 0; nt < 4; ++nt) { ffrag z = {0.f, 0.f, 0.f, 0.f}; acc2[mt][nt] = z; }

  for (int ch = 0; ch < 16; ++ch) {
    glds_stage<512>(WS, g_wt + 262144 + ch * 64 * 256, 256, 32768);
    __syncthreads();
    ffrag a1[2];
    { ffrag z = {0.f, 0.f, 0.f, 0.f}; a1[0] = z; a1[1] = z; }
    #pragma unroll
    for (int ks = 0; ks < 8; ++ks) {
      const bfrag a = ldfrag(WS, mq * 16, ks * 32, 256);
      const bfrag bb0 = ldfrag(H2, nq * 16, ks * 32, 256);
      const bfrag bb1 = ldfrag(H2, (nq + 1) * 16, ks * 32, 256);
      a1[0] = MFMA16(a, bb0, a1[0]);
      a1[1] = MFMA16(a, bb1, a1[1]);
    }
    __syncthreads();   // WS(w1) reads done

    // bias + exact GELU -> HD; then stage w2 chunk [256 outcols][64 k]
    const int c0 = mq * 16 + ((l >> 4) << 2);
    const float4 b14 = *(const float4*)(b1 + ch * 64 + c0);
    #pragma unroll
    for (int nt = 0; nt < 2; ++nt) {
      const int rr = (nq + nt) * 16 + (l & 15);
      const float u0 = a1[nt][0] + b14.x, u1 = a1[nt][1] + b14.y;
      const float u2 = a1[nt][2] + b14.z, u3 = a1[nt][3] + b14.w;
      const float g0 = 0.5f * u0 * (1.f + erff(u0 * 0.70710678118654752f));
      const float g1 = 0.5f * u1 * (1.f + erff(u1 * 0.70710678118654752f));
      const float g2 = 0.5f * u2 * (1.f + erff(u2 * 0.70710678118654752f));
      const float g3 = 0.5f * u3 * (1.f + erff(u3 * 0.70710678118654752f));
      *(unsigned*)(HD + swz(rr, c0, 64)) = pk2(g0, g1);
      *(unsigned*)(HD + swz(rr, c0 + 2, 64)) = pk2(g2, g3);
    }
    glds_stage<128>(WS, g_wt + 524288 + ch * 64, 1024, 32768);
    __syncthreads();

    // GEMM2: wave handles outcols wv*32..+31 (m-tiles 2wv, 2wv+1), all 4 n-tiles
    #pragma unroll
    for (int ks = 0; ks < 2; ++ks) {
      const bfrag am0 = ldfrag(WS, (wv * 2) * 16, ks * 32, 64);
      const bfrag am1 = ldfrag(WS, (wv * 2 + 1) * 16, ks * 32, 64);
      #pragma unroll
      for (int nt = 0; nt < 4; ++nt) {
        const bfrag bb = ldfrag(HD, nt * 16, ks * 32, 64);
        acc2[0][nt] = MFMA16(am0, bb, acc2[0][nt]);
        acc2[1][nt] = MFMA16(am1, bb, acc2[1][nt]);
      }
    }
    __syncthreads();   // WS/HD reads done before next chunk
  }

  #pragma unroll
  for (int mt = 0; mt < 2; ++mt) {
    const int c0 = (wv * 2 + mt) * 16 + ((l >> 4) << 2);
    const float4 b24 = *(const float4*)(b2 + c0);
    #pragma unroll
    for (int nt = 0; nt < 4; ++nt) {
      const long row = base + nt * 16 + (l & 15);
      const float4 xv = *(const float4*)(x + row * 256 + c0);
      const uint2 ov = *(const uint2*)(outw + row * 256 + c0);
      float4 res;
      res.x = acc2[mt][nt][0] + b24.x + xv.x + bf2f(ov.x & 0xFFFFu);
      res.y = acc2[mt][nt][1] + b24.y + xv.y + bf2f(ov.x >> 16);
      res.z = acc2[mt][nt][2] + b24.z + xv.z + bf2f(ov.y & 0xFFFFu);
      res.w = acc2[mt][nt][3] + b24.w + xv.w + bf2f(ov.y >> 16);
      *(float4*)(y + row * 256 + c0) = res;
    }
  }
}

extern "C" void kernel_launch(void* const* d_in, const int* in_sizes, int n_in,
                              void* d_out, int out_size, void* d_ws, size_t ws_size,
                              hipStream_t stream) {
  (void)in_sizes; (void)n_in; (void)out_size; (void)ws_size;
  const float* x      = (const float*)d_in[0];
  const float* qkv_w  = (const float*)d_in[1];
  const float* qkv_b  = (const float*)d_in[2];
  const float* proj_w = (const float*)d_in[3];
  const float* proj_b = (const float*)d_in[4];
  const float* rpb    = (const float*)d_in[5];
  const float* ln1g   = (const float*)d_in[6];
  const float* ln1b   = (const float*)d_in[7];
  const float* ln2g   = (const float*)d_in[8];
  const float* ln2b   = (const float*)d_in[9];
  const float* w1     = (const float*)d_in[10];
  const float* b1     = (const float*)d_in[11];
  const float* w2     = (const float*)d_in[12];
  const float* b2     = (const float*)d_in[13];
  float* y = (float*)d_out;
  char* ws = (char*)d_ws;

  // Workspace (peak exactly 268,435,456 B):
  //   phase A (per 4-batch group): XB [0,32M) | QKV [32M,128M) | Obuf [128M,256M)
  //   phase B: outw bf16 [0,128M) over dead XB/QKV; Obuf consumed by proj.
  unsigned short* XB   = (unsigned short*)(ws);
  unsigned short* QKV  = (unsigned short*)(ws + 33554432);
  unsigned short* Obuf = (unsigned short*)(ws + 134217728);
  unsigned short* outw = (unsigned short*)(ws);

  hipLaunchKernelGGL(conv_w, dim3(1536), dim3(256), 0, stream, qkv_w, proj_w, w1, w2);
  for (int g = 0; g < 4; ++g) {
    hipLaunchKernelGGL(ln1_k, dim3(8192), dim3(512), 0, stream,
                       x, ln1g, ln1b, XB, (long)g * 65536);
    hipLaunchKernelGGL(gemm_qkv, dim3(512, 6), dim3(512), 0, stream, XB, qkv_b, QKV);
    hipLaunchKernelGGL(attn_core, dim3(1024), dim3(512), 0, stream, QKV, rpb, Obuf, g * 4);
  }
  hipLaunchKernelGGL(gemm_proj, dim3(2048, 2), dim3(512), 0, stream, Obuf, proj_b, outw);
  hipLaunchKernelGGL(swin_mlp, dim3(4096), dim3(512), 0, stream,
                     x, outw, ln2g, ln2b, b1, b2, y);
}